// Round 10
// baseline (358.483 us; speedup 1.0000x reference)
//
#include <hip/hip_runtime.h>

#define BDIM 2
#define SEQ  1568
#define DIM  768
#define NH   12
#define FR   8
#define NTOK 196
#define HD   64
#define MTOT (BDIM*SEQ)   // 3136 token rows
#define M2   (MTOT*FR)    // 25088 (t,f) rows

typedef __attribute__((ext_vector_type(8))) short s16x8;
typedef __attribute__((ext_vector_type(4))) float f32x4;

static __device__ __forceinline__ float bf2f(ushort u) {
  return __uint_as_float(((unsigned)u) << 16);
}
static __device__ __forceinline__ ushort f2bf(float f) {
  unsigned u = __float_as_uint(f);
  unsigned r = (u + 0x7fffu + ((u >> 16) & 1u)) >> 16;
  return (ushort)r;
}
static __device__ __forceinline__ f32x4 mfma16(s16x8 a, s16x8 b, f32x4 c) {
  return __builtin_amdgcn_mfma_f32_16x16x32_bf16(a, b, c, 0, 0, 0);
}
static __device__ __forceinline__ void gload_lds16(const ushort* g, ushort* l) {
  __builtin_amdgcn_global_load_lds(
      (const __attribute__((address_space(1))) void*)g,
      (__attribute__((address_space(3))) void*)l, 16, 0, 0);
}

// ---------------------------------------------------------------------------
// Fused convert: inputs -> bf16 AND all 5 weights transposed -> bf16.
// ---------------------------------------------------------------------------
__global__ __launch_bounds__(256)
void cvt_all(const float* __restrict__ xq, const float* __restrict__ xk,
             ushort* __restrict__ xqbf, ushort* __restrict__ xkbf,
             const float* __restrict__ Wq, const float* __restrict__ Wkv,
             const float* __restrict__ Wpq, const float* __restrict__ Wproj,
             const float* __restrict__ Wpkv,
             ushort* __restrict__ WqT, ushort* __restrict__ WkvT,
             ushort* __restrict__ WpqT, ushort* __restrict__ WprT,
             ushort* __restrict__ WpkvT, int n4) {
  __shared__ float T[64][65];
  const int blk = blockIdx.x;
  const int tid = threadIdx.x;

  if (blk < 4704) {             // input conversion
    int i = blk*256 + tid;
    const float* src; ushort* dst; int j;
    if (i < n4)        { src = xq; dst = xqbf; j = i; }
    else               { src = xk; dst = xkbf; j = i - n4; }
    float4 v = ((const float4*)src)[j];
    ushort4 o; o.x = f2bf(v.x); o.y = f2bf(v.y); o.z = f2bf(v.z); o.w = f2bf(v.w);
    ((ushort4*)dst)[j] = o;
    return;
  }

  int idx = blk - 4704;
  const int wid = idx / 288; idx %= 288;
  const int ky = idx / 24;
  const int nx = idx % 24;
  const float* W; ushort* WT; int N;
  switch (wid) {
    case 0: W = Wq;    WT = WqT;   N = DIM;   break;
    case 1: W = Wkv;   WT = WkvT;  N = 2*DIM; break;
    case 2: W = Wpq;   WT = WpqT;  N = DIM;   break;
    case 3: W = Wproj; WT = WprT;  N = DIM;   break;
    default: W = Wpkv; WT = WpkvT; N = 2*DIM; break;
  }
  if (nx >= N/64) return;
  #pragma unroll
  for (int it = 0; it < 4; it++) {
    int id2 = it*256 + tid;
    int r = id2 >> 4, c4 = (id2 & 15) << 2;
    float4 v = *(const float4*)&W[(size_t)(ky*64 + r)*N + nx*64 + c4];
    T[r][c4+0] = v.x; T[r][c4+1] = v.y; T[r][c4+2] = v.z; T[r][c4+3] = v.w;
  }
  __syncthreads();
  #pragma unroll
  for (int it = 0; it < 4; it++) {
    int id2 = it*256 + tid;
    int n = id2 >> 4, k4 = (id2 & 15) << 2;
    ushort4 o;
    o.x = f2bf(T[k4+0][n]); o.y = f2bf(T[k4+1][n]);
    o.z = f2bf(T[k4+2][n]); o.w = f2bf(T[k4+3][n]);
    *(ushort4*)&WT[(size_t)(nx*64 + n)*DIM + ky*64 + k4] = o;
  }
}

// Vt[(b,f,h)][64][224] bf16, zero-padded n>=196. grid = 192
__global__ __launch_bounds__(256)
void vtrans(const ushort* __restrict__ kvbf, ushort* __restrict__ Vt) {
  __shared__ ushort Vl[NTOK][72];
  const int x = blockIdx.x;
  const int h = x % NH, f = (x / NH) % FR, b = x / (NH*FR);
  const int tid = threadIdx.x;
  for (int idx = tid; idx < NTOK*16; idx += 256) {
    int n = idx >> 4, c4 = (idx & 15) << 2;
    const ushort* p = kvbf + (size_t)(b*SEQ + f*NTOK + n)*(2*DIM) + DIM + h*HD + c4;
    *(ushort4*)&Vl[n][c4] = *(const ushort4*)p;
  }
  __syncthreads();
  ushort* vb = Vt + (size_t)x * (HD*224);
  for (int idx = tid; idx < 64*56; idx += 256) {
    int d = idx / 56, n4 = (idx % 56) << 2;
    ushort4 o;
    o.x = (n4+0 < NTOK) ? Vl[n4+0][d] : (ushort)0;
    o.y = (n4+1 < NTOK) ? Vl[n4+1][d] : (ushort)0;
    o.z = (n4+2 < NTOK) ? Vl[n4+2][d] : (ushort)0;
    o.w = (n4+3 < NTOK) ? Vl[n4+3][d] : (ushort)0;
    *(ushort4*)&vb[(size_t)d*224 + n4] = o;
  }
}

// ---------------------------------------------------------------------------
// Merged q+kv projection, 128x64 tiles. grid (36, 25).
// ---------------------------------------------------------------------------
__global__ __launch_bounds__(256)
void proj_pair(const ushort* __restrict__ xqbf, const ushort* __restrict__ xkbf,
               const ushort* __restrict__ WqT, const ushort* __restrict__ WkvT,
               ushort* __restrict__ qbf, ushort* __restrict__ kvbf)
{
  __shared__ ushort As[128][32];
  __shared__ ushort Bs[64][32];
  const int bx = blockIdx.x, by = blockIdx.y;
  const ushort* A; const ushort* Bt; ushort* C; int N, col0; float scale;
  if (bx < 12) { A = xqbf; Bt = WqT;  C = qbf;  N = DIM;   col0 = bx*64;      scale = 0.125f; }
  else         { A = xkbf; Bt = WkvT; C = kvbf; N = 2*DIM; col0 = (bx-12)*64; scale = 1.0f; }

  const int tid = threadIdx.x;
  const int w = tid >> 6, lane = tid & 63;
  const int lq = lane & 15, quad = lane >> 4;
  const int lrow = tid >> 2, lcol = (tid & 3) << 3;

  int ar0 = by*128 + lrow;       if (ar0 > MTOT-1) ar0 = MTOT-1;
  int ar1 = by*128 + 64 + lrow;  if (ar1 > MTOT-1) ar1 = MTOT-1;
  const size_t aoff0 = (size_t)ar0*DIM + lcol;
  const size_t aoff1 = (size_t)ar1*DIM + lcol;
  const size_t boff  = (size_t)(col0 + lrow)*DIM + lcol;

  f32x4 acc[2][4] = {};
  for (int k0 = 0; k0 < DIM; k0 += 32) {
    __syncthreads();
    gload_lds16(A  + aoff0 + k0, &As[w*16][0]);
    gload_lds16(A  + aoff1 + k0, &As[64 + w*16][0]);
    gload_lds16(Bt + boff  + k0, &Bs[w*16][0]);
    __syncthreads();
    s16x8 af[2], bw[4];
    #pragma unroll
    for (int i = 0; i < 2; i++) af[i] = *(const s16x8*)&As[w*32 + i*16 + lq][quad*8];
    #pragma unroll
    for (int j = 0; j < 4; j++) bw[j] = *(const s16x8*)&Bs[j*16 + lq][quad*8];
    #pragma unroll
    for (int i = 0; i < 2; i++)
      #pragma unroll
      for (int j = 0; j < 4; j++)
        acc[i][j] = mfma16(af[i], bw[j], acc[i][j]);
  }

  #pragma unroll
  for (int i = 0; i < 2; i++) {
    #pragma unroll
    for (int r = 0; r < 4; r++) {
      int row = by*128 + w*32 + i*16 + quad*4 + r;
      if (row < MTOT) {
        #pragma unroll
        for (int j = 0; j < 4; j++)
          C[(size_t)row*N + col0 + j*16 + lq] = f2bf(acc[i][j][r] * scale);
      }
    }
  }
}

// ---------------------------------------------------------------------------
// 128x64-tile GEMM for q2diag / outproj. grid (N/64, ceil(M/128)). K=768.
// ---------------------------------------------------------------------------
template<bool BIAS, bool DIAG>
__global__ __launch_bounds__(256)
void gemm64(const ushort* __restrict__ A, const ushort* __restrict__ Bt,
            float* __restrict__ C, const float* __restrict__ bias,
            int M, int N, float scale)
{
  __shared__ ushort As[128][32];
  __shared__ ushort Bs[64][32];
  const int bx = blockIdx.x, by = blockIdx.y;
  const int tid = threadIdx.x;
  const int w = tid >> 6, lane = tid & 63;
  const int lq = lane & 15, quad = lane >> 4;
  const int lrow = tid >> 2, lcol = (tid & 3) << 3;
  const int col0 = bx*64;

  int ar0 = by*128 + lrow;       if (ar0 > M-1) ar0 = M-1;
  int ar1 = by*128 + 64 + lrow;  if (ar1 > M-1) ar1 = M-1;
  size_t aoff0, aoff1;
  if (DIAG) {
    int f0 = (ar0 % SEQ) / NTOK, f1 = (ar1 % SEQ) / NTOK;
    aoff0 = ((size_t)ar0*FR + f0)*DIM + lcol;
    aoff1 = ((size_t)ar1*FR + f1)*DIM + lcol;
  } else {
    aoff0 = (size_t)ar0*DIM + lcol;
    aoff1 = (size_t)ar1*DIM + lcol;
  }
  const size_t boff = (size_t)(col0 + lrow)*DIM + lcol;

  f32x4 acc[2][4] = {};
  for (int k0 = 0; k0 < DIM; k0 += 32) {
    __syncthreads();
    gload_lds16(A  + aoff0 + k0, &As[w*16][0]);
    gload_lds16(A  + aoff1 + k0, &As[64 + w*16][0]);
    gload_lds16(Bt + boff  + k0, &Bs[w*16][0]);
    __syncthreads();
    s16x8 af[2], bw[4];
    #pragma unroll
    for (int i = 0; i < 2; i++) af[i] = *(const s16x8*)&As[w*32 + i*16 + lq][quad*8];
    #pragma unroll
    for (int j = 0; j < 4; j++) bw[j] = *(const s16x8*)&Bs[j*16 + lq][quad*8];
    #pragma unroll
    for (int i = 0; i < 2; i++)
      #pragma unroll
      for (int j = 0; j < 4; j++)
        acc[i][j] = mfma16(af[i], bw[j], acc[i][j]);
  }

  #pragma unroll
  for (int i = 0; i < 2; i++) {
    #pragma unroll
    for (int r = 0; r < 4; r++) {
      int row = by*128 + w*32 + i*16 + quad*4 + r;
      if (row < M) {
        #pragma unroll
        for (int j = 0; j < 4; j++) {
          int col = col0 + j*16 + lq;
          float v = acc[i][j][r] * scale;
          if (BIAS) v += bias[col];
          C[(size_t)row*N + col] = v;
        }
      }
    }
  }
}

// ---------------------------------------------------------------------------
// FUSED stage-2: one kernel computes, per block (by,bx∈0..5):
//   acc_k = x_tile @ Wk_panel, acc_v = x_tile @ Wv_panel (A staged ONCE)
//   logits p = acc_k · q2 (per 2 heads, in-tile), softmax over f via
//   register shuffles (f-halves pair via lane^16), attn2 written directly,
//   z = sum_f a2 * acc_v rows written bf16. No Lg global, no a2 LDS.
// grid (196 by-major, 6 bx). LDS 32KB; acc = 128 VGPRs -> ~2 blocks/CU.
// ---------------------------------------------------------------------------
__global__ __launch_bounds__(256)
void stage2_gemm(const ushort* __restrict__ A, const ushort* __restrict__ Wk,
                 const ushort* __restrict__ Wv, const float* __restrict__ q2,
                 ushort* __restrict__ zbf, float* __restrict__ attn2)
{
  __shared__ ushort As[128][32];
  __shared__ ushort Bks[128][32];
  __shared__ ushort Bvs[128][32];
  __shared__ float  q2s[16][128];

  const int tid = threadIdx.x;
  const int by = blockIdx.x, bx = blockIdx.y;
  const int w = tid >> 6, lane = tid & 63;
  const int lq = lane & 15, quad = lane >> 4;
  const int wr = (w >> 1) * 64, wc = (w & 1) * 64;
  const int head = bx*2 + (wc >> 6);

  // stage q2 tile [16 tokens][128 cols] (visible after first k-loop barrier)
  {
    int tt = tid >> 4, c0 = (tid & 15) << 3;
    const float* src = q2 + (size_t)(by*16 + tt)*DIM + bx*128 + c0;
    *(float4*)&q2s[tt][c0]     = *(const float4*)src;
    *(float4*)&q2s[tt][c0 + 4] = *(const float4*)(src + 4);
  }

  const int lrow = tid >> 2, lcol = (tid & 3) << 3;
  const size_t aoff0 = (size_t)(by*128 + lrow)*DIM + lcol;
  const size_t aoff1 = (size_t)(by*128 + 64 + lrow)*DIM + lcol;
  const size_t boff0 = (size_t)(bx*128 + lrow)*DIM + lcol;
  const size_t boff1 = (size_t)(bx*128 + 64 + lrow)*DIM + lcol;

  f32x4 acck[4][4] = {};
  f32x4 accv[4][4] = {};

  for (int k0 = 0; k0 < DIM; k0 += 32) {
    __syncthreads();
    gload_lds16(A  + aoff0 + k0, &As[w*16][0]);
    gload_lds16(A  + aoff1 + k0, &As[64 + w*16][0]);
    gload_lds16(Wk + boff0 + k0, &Bks[w*16][0]);
    gload_lds16(Wk + boff1 + k0, &Bks[64 + w*16][0]);
    gload_lds16(Wv + boff0 + k0, &Bvs[w*16][0]);
    gload_lds16(Wv + boff1 + k0, &Bvs[64 + w*16][0]);
    __syncthreads();
    s16x8 af[4];
    #pragma unroll
    for (int i = 0; i < 4; i++) af[i] = *(const s16x8*)&As[wr + i*16 + lq][quad*8];
    #pragma unroll
    for (int j = 0; j < 4; j++) {
      s16x8 bk = *(const s16x8*)&Bks[wc + j*16 + lq][quad*8];
      #pragma unroll
      for (int i = 0; i < 4; i++) acck[i][j] = mfma16(af[i], bk, acck[i][j]);
      s16x8 bv = *(const s16x8*)&Bvs[wc + j*16 + lq][quad*8];
      #pragma unroll
      for (int i = 0; i < 4; i++) accv[i][j] = mfma16(af[i], bv, accv[i][j]);
    }
  }

  // ---- epilogue: logits -> softmax -> attn2 + z, all in registers ----
  #pragma unroll
  for (int i = 0; i < 4; i++) {
    const int tt = ((wr + i*16) >> 3) + (quad >> 1);   // token within tile
    // logits for rows (tt, f = (quad&1)*4 + r)
    float p[4];
    #pragma unroll
    for (int r = 0; r < 4; r++) {
      float s = 0.f;
      #pragma unroll
      for (int j = 0; j < 4; j++)
        s += acck[i][j][r] * q2s[tt][wc + j*16 + lq];
      s += __shfl_xor(s, 1); s += __shfl_xor(s, 2);
      s += __shfl_xor(s, 4); s += __shfl_xor(s, 8);
      p[r] = s;
    }
    // softmax over f: 4 in-lane + partner quad (lane^16)
    float m = fmaxf(fmaxf(p[0], p[1]), fmaxf(p[2], p[3]));
    m = fmaxf(m, __shfl_xor(m, 16));
    float a[4]; float ssum = 0.f;
    #pragma unroll
    for (int r = 0; r < 4; r++) { a[r] = __expf(p[r] - m); ssum += a[r]; }
    ssum += __shfl_xor(ssum, 16);
    float inv = 1.0f / ssum;
    #pragma unroll
    for (int r = 0; r < 4; r++) a[r] *= inv;

    const int tg = by*16 + tt;
    // attn2 write: 4 consecutive f per lane, from lq==0
    if (lq == 0) {
      int b = tg / SEQ, sda = tg % SEQ;
      int f0 = (quad & 1) * 4;
      float4 av; av.x = a[0]; av.y = a[1]; av.z = a[2]; av.w = a[3];
      *(float4*)&attn2[((size_t)(b*NH + head)*SEQ + sda)*FR + f0] = av;
    }
    // zsum: weight V-rows by a, combine f-halves via lane^16
    float zj[4];
    #pragma unroll
    for (int j = 0; j < 4; j++) {
      float s = accv[i][j][0]*a[0] + accv[i][j][1]*a[1]
              + accv[i][j][2]*a[2] + accv[i][j][3]*a[3];
      zj[j] = s + __shfl_xor(s, 16);
    }
    if ((quad & 1) == 0) {
      #pragma unroll
      for (int j = 0; j < 4; j++)
        zbf[(size_t)tg*DIM + bx*128 + wc + j*16 + lq] = f2bf(zj[j]);
    }
  }
}

// ---------------------------------------------------------------------------
// Stage 1 (unchanged from round 9): XCD-local grid, K LDS-shared, P aliases
// Ks, coalesced x-store via per-wave LDS transpose.
// ---------------------------------------------------------------------------
__global__ __launch_bounds__(256)
void stage1_mfma(const ushort* __restrict__ qbf, const ushort* __restrict__ kvbf,
                 const ushort* __restrict__ Vt, ushort* __restrict__ x)
{
  __shared__ ushort sh[208*72];

  const int bh = blockIdx.x;
  const int f  = blockIdx.y;
  const int qt = blockIdx.z;
  const int b = bh / NH, h = bh % NH;
  const int tid = threadIdx.x;
  const int w = tid >> 6, lane = tid & 63;
  const int lq = lane & 15, quad = lane >> 4;

  int srow = qt*64 + w*16 + lq; if (srow > SEQ-1) srow = SEQ-1;
  const ushort* qp = qbf + ((size_t)b*SEQ + srow)*DIM + h*HD + quad*8;
  s16x8 aq0 = *(const s16x8*)(qp);
  s16x8 aq1 = *(const s16x8*)(qp + 32);

  const int krow = tid >> 3, kcol = (tid & 7) << 3;
  const ushort* kbase = kvbf + ((size_t)b*SEQ + f*NTOK)*(2*DIM) + h*HD + kcol;
  #pragma unroll
  for (int p = 0; p < 7; p++) {
    int row = krow + p*32;
    if (row < 208) {
      if (row < NTOK) {
        *(s16x8*)&sh[row*72 + kcol] = *(const s16x8*)(kbase + (size_t)row*(2*DIM));
      } else {
        ushort4 z4; z4.x = 0; z4.y = 0; z4.z = 0; z4.w = 0;
        *(ushort4*)&sh[row*72 + kcol]     = z4;
        *(ushort4*)&sh[row*72 + kcol + 4] = z4;
      }
    }
  }
  __syncthreads();

  f32x4 acc[13];
  #pragma unroll
  for (int nt = 0; nt < 13; nt++) {
    s16x8 bk0 = *(const s16x8*)&sh[(nt*16 + lq)*72 + quad*8];
    s16x8 bk1 = *(const s16x8*)&sh[(nt*16 + lq)*72 + 32 + quad*8];
    f32x4 c = {};
    c = mfma16(aq0, bk0, c);
    c = mfma16(aq1, bk1, c);
    acc[nt] = c;
  }

  float sm[4] = {0.f, 0.f, 0.f, 0.f};
  #pragma unroll
  for (int nt = 0; nt < 13; nt++) {
    bool valid = (nt < 12) || (lq < 4);
    #pragma unroll
    for (int r = 0; r < 4; r++) {
      float e = valid ? __expf(acc[nt][r]) : 0.f;
      acc[nt][r] = e; sm[r] += e;
    }
  }
  #pragma unroll
  for (int r = 0; r < 4; r++) {
    float s = sm[r];
    s += __shfl_xor(s, 1); s += __shfl_xor(s, 2);
    s += __shfl_xor(s, 4); s += __shfl_xor(s, 8);
    sm[r] = 1.0f / s;
  }

  __syncthreads();

  ushort* Pw = sh + w*(16*232);
  {
    ushort4 zz; zz.x = 0; zz.y = 0; zz.z = 0; zz.w = 0;
    *(ushort4*)&Pw[lq*232 + 208 + quad*4] = zz;
  }
  #pragma unroll
  for (int nt = 0; nt < 13; nt++)
    #pragma unroll
    for (int r = 0; r < 4; r++)
      Pw[(quad*4 + r)*232 + nt*16 + lq] = f2bf(acc[nt][r] * sm[r]);

  const ushort* vb = Vt + ((size_t)((b*FR + f)*NH + h)) * (HD*224);
  f32x4 o[4] = {};
  #pragma unroll
  for (int ks = 0; ks < 7; ks++) {
    s16x8 ap = *(const s16x8*)&Pw[lq*232 + ks*32 + quad*8];
    #pragma unroll
    for (int dt = 0; dt < 4; dt++) {
      s16x8 bv = *(const s16x8*)(vb + (size_t)(dt*16 + lq)*224 + ks*32 + quad*8);
      o[dt] = mfma16(ap, bv, o[dt]);
    }
  }

  #pragma unroll
  for (int dt = 0; dt < 4; dt++)
    #pragma unroll
    for (int r = 0; r < 4; r++)
      Pw[(quad*4 + r)*232 + dt*16 + lq] = f2bf(o[dt][r]);

  {
    int rrow = lane >> 2;
    int cb = (lane & 3) << 4;
    s16x8 xv0 = *(const s16x8*)&Pw[rrow*232 + cb];
    s16x8 xv1 = *(const s16x8*)&Pw[rrow*232 + cb + 8];
    int s = qt*64 + w*16 + rrow;
    if (s < SEQ) {
      ushort* xp = x + (((size_t)b*SEQ + s)*FR + f)*DIM + h*HD + cb;
      *(s16x8*)xp       = xv0;
      *(s16x8*)(xp + 8) = xv1;
    }
  }
}

// ---------------------------------------------------------------------------
// Workspace (ushort units; same known-good map as rounds 8-9):
//  xbf | kvbf (q2 fp32 alias) | qbf (zbf alias) | xqbf (Vt alias) | xkbf
//  WqT | WkvT | WpqT | WprT | WpkvT
// ---------------------------------------------------------------------------
extern "C" void kernel_launch(void* const* d_in, const int* in_sizes, int n_in,
                              void* d_out, int out_size, void* d_ws, size_t ws_size,
                              hipStream_t stream) {
  const float* xq    = (const float*)d_in[0];
  const float* xk    = (const float*)d_in[1];
  const float* Wq    = (const float*)d_in[2];
  const float* Wkv   = (const float*)d_in[3];
  const float* Wpq   = (const float*)d_in[4];
  const float* Wpkv  = (const float*)d_in[5];
  const float* Wproj = (const float*)d_in[6];
  const float* bproj = (const float*)d_in[7];

  float* out   = (float*)d_out;
  float* attn2 = out + (size_t)MTOT*DIM;

  ushort* ws    = (ushort*)d_ws;
  ushort* xbf   = ws;
  ushort* kvbf  = xbf + (size_t)MTOT*FR*DIM;
  float*  q2    = (float*)kvbf;                 // alias, post-stage1
  ushort* qbf   = kvbf + (size_t)MTOT*2*DIM;
  ushort* zbf   = qbf;                          // alias, post-stage1
  ushort* xqbf  = qbf + (size_t)MTOT*DIM;
  ushort* xkbf  = xqbf + (size_t)MTOT*DIM;
  ushort* Vt    = xqbf;                         // alias (dead post-proj)
  ushort* WqT   = xkbf + (size_t)MTOT*DIM;
  ushort* WkvT  = WqT  + (size_t)DIM*DIM;
  ushort* WpqT  = WkvT + (size_t)2*DIM*DIM;
  ushort* WprT  = WpqT + (size_t)DIM*DIM;
  ushort* WpkvT = WprT + (size_t)DIM*DIM;

  dim3 blk(256);
  const int n4 = MTOT*DIM/4;

  cvt_all<<<dim3(4704 + 1440), blk, 0, stream>>>(
      xq, xk, xqbf, xkbf, Wq, Wkv, Wpq, Wproj, Wpkv,
      WqT, WkvT, WpqT, WprT, WpkvT, n4);

  proj_pair<<<dim3(36, (MTOT+127)/128), blk, 0, stream>>>(
      xqbf, xkbf, WqT, WkvT, qbf, kvbf);
  vtrans<<<dim3(BDIM*FR*NH), blk, 0, stream>>>(kvbf, Vt);
  stage1_mfma<<<dim3(BDIM*NH, FR, (SEQ+63)/64), blk, 0, stream>>>(qbf, kvbf, Vt, xbf);
  gemm64<false,true><<<dim3(12, (MTOT+127)/128), blk, 0, stream>>>(
      xbf, WpqT, q2, nullptr, MTOT, DIM, 0.125f);
  // fused stage-2: logits + softmax + attn2 + z in one pass over x
  stage2_gemm<<<dim3(M2/128, 6), blk, 0, stream>>>(
      xbf, WpkvT, WpkvT + (size_t)DIM*DIM, q2, zbf, attn2);
  gemm64<true,false><<<dim3(12, (MTOT+127)/128), blk, 0, stream>>>(
      zbf, WprT, out, bproj, MTOT, DIM, 1.0f);
}

// Round 11
// 317.045 us; speedup vs baseline: 1.1307x; 1.1307x over previous
//
#include <hip/hip_runtime.h>

#define BDIM 2
#define SEQ  1568
#define DIM  768
#define NH   12
#define FR   8
#define NTOK 196
#define HD   64
#define MTOT (BDIM*SEQ)   // 3136 token rows
#define M2   (MTOT*FR)    // 25088 (t,f) rows

typedef __attribute__((ext_vector_type(8))) short s16x8;
typedef __attribute__((ext_vector_type(4))) float f32x4;

static __device__ __forceinline__ float bf2f(ushort u) {
  return __uint_as_float(((unsigned)u) << 16);
}
static __device__ __forceinline__ ushort f2bf(float f) {
  unsigned u = __float_as_uint(f);
  unsigned r = (u + 0x7fffu + ((u >> 16) & 1u)) >> 16;
  return (ushort)r;
}
static __device__ __forceinline__ f32x4 mfma16(s16x8 a, s16x8 b, f32x4 c) {
  return __builtin_amdgcn_mfma_f32_16x16x32_bf16(a, b, c, 0, 0, 0);
}
static __device__ __forceinline__ void gload_lds16(const ushort* g, ushort* l) {
  __builtin_amdgcn_global_load_lds(
      (const __attribute__((address_space(1))) void*)g,
      (__attribute__((address_space(3))) void*)l, 16, 0, 0);
}

// ---------------------------------------------------------------------------
// Fused convert: inputs -> bf16 AND all 5 weights transposed -> bf16.
// ---------------------------------------------------------------------------
__global__ __launch_bounds__(256)
void cvt_all(const float* __restrict__ xq, const float* __restrict__ xk,
             ushort* __restrict__ xqbf, ushort* __restrict__ xkbf,
             const float* __restrict__ Wq, const float* __restrict__ Wkv,
             const float* __restrict__ Wpq, const float* __restrict__ Wproj,
             const float* __restrict__ Wpkv,
             ushort* __restrict__ WqT, ushort* __restrict__ WkvT,
             ushort* __restrict__ WpqT, ushort* __restrict__ WprT,
             ushort* __restrict__ WpkvT, int n4) {
  __shared__ float T[64][65];
  const int blk = blockIdx.x;
  const int tid = threadIdx.x;

  if (blk < 4704) {             // input conversion
    int i = blk*256 + tid;
    const float* src; ushort* dst; int j;
    if (i < n4)        { src = xq; dst = xqbf; j = i; }
    else               { src = xk; dst = xkbf; j = i - n4; }
    float4 v = ((const float4*)src)[j];
    ushort4 o; o.x = f2bf(v.x); o.y = f2bf(v.y); o.z = f2bf(v.z); o.w = f2bf(v.w);
    ((ushort4*)dst)[j] = o;
    return;
  }

  int idx = blk - 4704;
  const int wid = idx / 288; idx %= 288;
  const int ky = idx / 24;
  const int nx = idx % 24;
  const float* W; ushort* WT; int N;
  switch (wid) {
    case 0: W = Wq;    WT = WqT;   N = DIM;   break;
    case 1: W = Wkv;   WT = WkvT;  N = 2*DIM; break;
    case 2: W = Wpq;   WT = WpqT;  N = DIM;   break;
    case 3: W = Wproj; WT = WprT;  N = DIM;   break;
    default: W = Wpkv; WT = WpkvT; N = 2*DIM; break;
  }
  if (nx >= N/64) return;
  #pragma unroll
  for (int it = 0; it < 4; it++) {
    int id2 = it*256 + tid;
    int r = id2 >> 4, c4 = (id2 & 15) << 2;
    float4 v = *(const float4*)&W[(size_t)(ky*64 + r)*N + nx*64 + c4];
    T[r][c4+0] = v.x; T[r][c4+1] = v.y; T[r][c4+2] = v.z; T[r][c4+3] = v.w;
  }
  __syncthreads();
  #pragma unroll
  for (int it = 0; it < 4; it++) {
    int id2 = it*256 + tid;
    int n = id2 >> 4, k4 = (id2 & 15) << 2;
    ushort4 o;
    o.x = f2bf(T[k4+0][n]); o.y = f2bf(T[k4+1][n]);
    o.z = f2bf(T[k4+2][n]); o.w = f2bf(T[k4+3][n]);
    *(ushort4*)&WT[(size_t)(nx*64 + n)*DIM + ky*64 + k4] = o;
  }
}

// Vt[(b,f,h)][64][224] bf16, zero-padded n>=196. grid = 192
__global__ __launch_bounds__(256)
void vtrans(const ushort* __restrict__ kvbf, ushort* __restrict__ Vt) {
  __shared__ ushort Vl[NTOK][72];
  const int x = blockIdx.x;
  const int h = x % NH, f = (x / NH) % FR, b = x / (NH*FR);
  const int tid = threadIdx.x;
  for (int idx = tid; idx < NTOK*16; idx += 256) {
    int n = idx >> 4, c4 = (idx & 15) << 2;
    const ushort* p = kvbf + (size_t)(b*SEQ + f*NTOK + n)*(2*DIM) + DIM + h*HD + c4;
    *(ushort4*)&Vl[n][c4] = *(const ushort4*)p;
  }
  __syncthreads();
  ushort* vb = Vt + (size_t)x * (HD*224);
  for (int idx = tid; idx < 64*56; idx += 256) {
    int d = idx / 56, n4 = (idx % 56) << 2;
    ushort4 o;
    o.x = (n4+0 < NTOK) ? Vl[n4+0][d] : (ushort)0;
    o.y = (n4+1 < NTOK) ? Vl[n4+1][d] : (ushort)0;
    o.z = (n4+2 < NTOK) ? Vl[n4+2][d] : (ushort)0;
    o.w = (n4+3 < NTOK) ? Vl[n4+3][d] : (ushort)0;
    *(ushort4*)&vb[(size_t)d*224 + n4] = o;
  }
}

// ---------------------------------------------------------------------------
// Merged q+kv projection, 128x64 tiles. grid (36, 25).
// ---------------------------------------------------------------------------
__global__ __launch_bounds__(256)
void proj_pair(const ushort* __restrict__ xqbf, const ushort* __restrict__ xkbf,
               const ushort* __restrict__ WqT, const ushort* __restrict__ WkvT,
               ushort* __restrict__ qbf, ushort* __restrict__ kvbf)
{
  __shared__ ushort As[128][32];
  __shared__ ushort Bs[64][32];
  const int bx = blockIdx.x, by = blockIdx.y;
  const ushort* A; const ushort* Bt; ushort* C; int N, col0; float scale;
  if (bx < 12) { A = xqbf; Bt = WqT;  C = qbf;  N = DIM;   col0 = bx*64;      scale = 0.125f; }
  else         { A = xkbf; Bt = WkvT; C = kvbf; N = 2*DIM; col0 = (bx-12)*64; scale = 1.0f; }

  const int tid = threadIdx.x;
  const int w = tid >> 6, lane = tid & 63;
  const int lq = lane & 15, quad = lane >> 4;
  const int lrow = tid >> 2, lcol = (tid & 3) << 3;

  int ar0 = by*128 + lrow;       if (ar0 > MTOT-1) ar0 = MTOT-1;
  int ar1 = by*128 + 64 + lrow;  if (ar1 > MTOT-1) ar1 = MTOT-1;
  const size_t aoff0 = (size_t)ar0*DIM + lcol;
  const size_t aoff1 = (size_t)ar1*DIM + lcol;
  const size_t boff  = (size_t)(col0 + lrow)*DIM + lcol;

  f32x4 acc[2][4] = {};
  for (int k0 = 0; k0 < DIM; k0 += 32) {
    __syncthreads();
    gload_lds16(A  + aoff0 + k0, &As[w*16][0]);
    gload_lds16(A  + aoff1 + k0, &As[64 + w*16][0]);
    gload_lds16(Bt + boff  + k0, &Bs[w*16][0]);
    __syncthreads();
    s16x8 af[2], bw[4];
    #pragma unroll
    for (int i = 0; i < 2; i++) af[i] = *(const s16x8*)&As[w*32 + i*16 + lq][quad*8];
    #pragma unroll
    for (int j = 0; j < 4; j++) bw[j] = *(const s16x8*)&Bs[j*16 + lq][quad*8];
    #pragma unroll
    for (int i = 0; i < 2; i++)
      #pragma unroll
      for (int j = 0; j < 4; j++)
        acc[i][j] = mfma16(af[i], bw[j], acc[i][j]);
  }

  #pragma unroll
  for (int i = 0; i < 2; i++) {
    #pragma unroll
    for (int r = 0; r < 4; r++) {
      int row = by*128 + w*32 + i*16 + quad*4 + r;
      if (row < MTOT) {
        #pragma unroll
        for (int j = 0; j < 4; j++)
          C[(size_t)row*N + col0 + j*16 + lq] = f2bf(acc[i][j][r] * scale);
      }
    }
  }
}

// ---------------------------------------------------------------------------
// 128x64-tile GEMM for q2diag / outproj. grid (N/64, ceil(M/128)). K=768.
// ---------------------------------------------------------------------------
template<bool BIAS, bool DIAG>
__global__ __launch_bounds__(256)
void gemm64(const ushort* __restrict__ A, const ushort* __restrict__ Bt,
            float* __restrict__ C, const float* __restrict__ bias,
            int M, int N, float scale)
{
  __shared__ ushort As[128][32];
  __shared__ ushort Bs[64][32];
  const int bx = blockIdx.x, by = blockIdx.y;
  const int tid = threadIdx.x;
  const int w = tid >> 6, lane = tid & 63;
  const int lq = lane & 15, quad = lane >> 4;
  const int lrow = tid >> 2, lcol = (tid & 3) << 3;
  const int col0 = bx*64;

  int ar0 = by*128 + lrow;       if (ar0 > M-1) ar0 = M-1;
  int ar1 = by*128 + 64 + lrow;  if (ar1 > M-1) ar1 = M-1;
  size_t aoff0, aoff1;
  if (DIAG) {
    int f0 = (ar0 % SEQ) / NTOK, f1 = (ar1 % SEQ) / NTOK;
    aoff0 = ((size_t)ar0*FR + f0)*DIM + lcol;
    aoff1 = ((size_t)ar1*FR + f1)*DIM + lcol;
  } else {
    aoff0 = (size_t)ar0*DIM + lcol;
    aoff1 = (size_t)ar1*DIM + lcol;
  }
  const size_t boff = (size_t)(col0 + lrow)*DIM + lcol;

  f32x4 acc[2][4] = {};
  for (int k0 = 0; k0 < DIM; k0 += 32) {
    __syncthreads();
    gload_lds16(A  + aoff0 + k0, &As[w*16][0]);
    gload_lds16(A  + aoff1 + k0, &As[64 + w*16][0]);
    gload_lds16(Bt + boff  + k0, &Bs[w*16][0]);
    __syncthreads();
    s16x8 af[2], bw[4];
    #pragma unroll
    for (int i = 0; i < 2; i++) af[i] = *(const s16x8*)&As[w*32 + i*16 + lq][quad*8];
    #pragma unroll
    for (int j = 0; j < 4; j++) bw[j] = *(const s16x8*)&Bs[j*16 + lq][quad*8];
    #pragma unroll
    for (int i = 0; i < 2; i++)
      #pragma unroll
      for (int j = 0; j < 4; j++)
        acc[i][j] = mfma16(af[i], bw[j], acc[i][j]);
  }

  #pragma unroll
  for (int i = 0; i < 2; i++) {
    #pragma unroll
    for (int r = 0; r < 4; r++) {
      int row = by*128 + w*32 + i*16 + quad*4 + r;
      if (row < M) {
        #pragma unroll
        for (int j = 0; j < 4; j++) {
          int col = col0 + j*16 + lq;
          float v = acc[i][j][r] * scale;
          if (BIAS) v += bias[col];
          C[(size_t)row*N + col] = v;
        }
      }
    }
  }
}

// ---------------------------------------------------------------------------
// FUSED stage-2, v2 (64-row tiles to fix round-10's register/occupancy cliff):
// block (by in 0..391, bx in 0..5): 64 (t,f)-rows x 128 cols (2 heads) of
// BOTH x@Wk and x@Wv with A staged once; logits dot + softmax in registers
// (f-halves pair via lane^16); attn2 + z written directly.
// acc = 64 regs (2 mats x 2 i x 4 j) -> ~2 waves/SIMD. LDS 24 KB.
// grid (392, 6) by-major: bx-siblings at stride 392 = 0 mod 8 -> same XCD.
// ---------------------------------------------------------------------------
__global__ __launch_bounds__(256)
void stage2_gemm(const ushort* __restrict__ A, const ushort* __restrict__ Wk,
                 const ushort* __restrict__ Wv, const float* __restrict__ q2,
                 ushort* __restrict__ zbf, float* __restrict__ attn2)
{
  __shared__ ushort As[64][32];
  __shared__ ushort Bks[128][32];
  __shared__ ushort Bvs[128][32];
  __shared__ float  q2s[8][128];

  const int tid = threadIdx.x;
  const int by = blockIdx.x, bx = blockIdx.y;
  const int w = tid >> 6, lane = tid & 63;
  const int lq = lane & 15, quad = lane >> 4;
  const int wr = (w >> 1) * 32, wc = (w & 1) * 64;
  const int head = bx*2 + (wc >> 6);

  // stage q2 tile [8 tokens][128 cols] (visible after first k-loop barrier)
  {
    int tt = tid >> 5, c0 = (tid & 31) << 2;
    *(float4*)&q2s[tt][c0] =
        *(const float4*)(q2 + (size_t)(by*8 + tt)*DIM + bx*128 + c0);
  }

  const int lrow = tid >> 2, lcol = (tid & 3) << 3;
  const size_t aoff  = (size_t)(by*64 + lrow)*DIM + lcol;
  const size_t boff0 = (size_t)(bx*128 + lrow)*DIM + lcol;
  const size_t boff1 = (size_t)(bx*128 + 64 + lrow)*DIM + lcol;

  f32x4 acck[2][4] = {};
  f32x4 accv[2][4] = {};

  for (int k0 = 0; k0 < DIM; k0 += 32) {
    __syncthreads();
    gload_lds16(A  + aoff  + k0, &As[w*16][0]);
    gload_lds16(Wk + boff0 + k0, &Bks[w*16][0]);
    gload_lds16(Wk + boff1 + k0, &Bks[64 + w*16][0]);
    gload_lds16(Wv + boff0 + k0, &Bvs[w*16][0]);
    gload_lds16(Wv + boff1 + k0, &Bvs[64 + w*16][0]);
    __syncthreads();
    s16x8 af[2];
    #pragma unroll
    for (int i = 0; i < 2; i++) af[i] = *(const s16x8*)&As[wr + i*16 + lq][quad*8];
    #pragma unroll
    for (int j = 0; j < 4; j++) {
      s16x8 bk = *(const s16x8*)&Bks[wc + j*16 + lq][quad*8];
      #pragma unroll
      for (int i = 0; i < 2; i++) acck[i][j] = mfma16(af[i], bk, acck[i][j]);
      s16x8 bv = *(const s16x8*)&Bvs[wc + j*16 + lq][quad*8];
      #pragma unroll
      for (int i = 0; i < 2; i++) accv[i][j] = mfma16(af[i], bv, accv[i][j]);
    }
  }

  // ---- epilogue: logits -> softmax -> attn2 + z, all in registers ----
  #pragma unroll
  for (int i = 0; i < 2; i++) {
    const int tt = ((wr + i*16) >> 3) + (quad >> 1);   // token within tile (0..7)
    float p[4];
    #pragma unroll
    for (int r = 0; r < 4; r++) {
      float s = 0.f;
      #pragma unroll
      for (int j = 0; j < 4; j++)
        s += acck[i][j][r] * q2s[tt][wc + j*16 + lq];
      s += __shfl_xor(s, 1); s += __shfl_xor(s, 2);
      s += __shfl_xor(s, 4); s += __shfl_xor(s, 8);
      p[r] = s;
    }
    float m = fmaxf(fmaxf(p[0], p[1]), fmaxf(p[2], p[3]));
    m = fmaxf(m, __shfl_xor(m, 16));
    float a[4]; float ssum = 0.f;
    #pragma unroll
    for (int r = 0; r < 4; r++) { a[r] = __expf(p[r] - m); ssum += a[r]; }
    ssum += __shfl_xor(ssum, 16);
    float inv = 1.0f / ssum;
    #pragma unroll
    for (int r = 0; r < 4; r++) a[r] *= inv;

    const int tg = by*8 + tt;
    if (lq == 0) {
      int b = tg / SEQ, sda = tg % SEQ;
      int f0 = (quad & 1) * 4;
      float4 av; av.x = a[0]; av.y = a[1]; av.z = a[2]; av.w = a[3];
      *(float4*)&attn2[((size_t)(b*NH + head)*SEQ + sda)*FR + f0] = av;
    }
    float zj[4];
    #pragma unroll
    for (int j = 0; j < 4; j++) {
      float s = accv[i][j][0]*a[0] + accv[i][j][1]*a[1]
              + accv[i][j][2]*a[2] + accv[i][j][3]*a[3];
      zj[j] = s + __shfl_xor(s, 16);
    }
    if ((quad & 1) == 0) {
      #pragma unroll
      for (int j = 0; j < 4; j++)
        zbf[(size_t)tg*DIM + bx*128 + wc + j*16 + lq] = f2bf(zj[j]);
    }
  }
}

// ---------------------------------------------------------------------------
// Stage 1 (unchanged): XCD-local grid, K LDS-shared, P aliases Ks,
// coalesced x-store via per-wave LDS transpose.
// ---------------------------------------------------------------------------
__global__ __launch_bounds__(256)
void stage1_mfma(const ushort* __restrict__ qbf, const ushort* __restrict__ kvbf,
                 const ushort* __restrict__ Vt, ushort* __restrict__ x)
{
  __shared__ ushort sh[208*72];

  const int bh = blockIdx.x;
  const int f  = blockIdx.y;
  const int qt = blockIdx.z;
  const int b = bh / NH, h = bh % NH;
  const int tid = threadIdx.x;
  const int w = tid >> 6, lane = tid & 63;
  const int lq = lane & 15, quad = lane >> 4;

  int srow = qt*64 + w*16 + lq; if (srow > SEQ-1) srow = SEQ-1;
  const ushort* qp = qbf + ((size_t)b*SEQ + srow)*DIM + h*HD + quad*8;
  s16x8 aq0 = *(const s16x8*)(qp);
  s16x8 aq1 = *(const s16x8*)(qp + 32);

  const int krow = tid >> 3, kcol = (tid & 7) << 3;
  const ushort* kbase = kvbf + ((size_t)b*SEQ + f*NTOK)*(2*DIM) + h*HD + kcol;
  #pragma unroll
  for (int p = 0; p < 7; p++) {
    int row = krow + p*32;
    if (row < 208) {
      if (row < NTOK) {
        *(s16x8*)&sh[row*72 + kcol] = *(const s16x8*)(kbase + (size_t)row*(2*DIM));
      } else {
        ushort4 z4; z4.x = 0; z4.y = 0; z4.z = 0; z4.w = 0;
        *(ushort4*)&sh[row*72 + kcol]     = z4;
        *(ushort4*)&sh[row*72 + kcol + 4] = z4;
      }
    }
  }
  __syncthreads();

  f32x4 acc[13];
  #pragma unroll
  for (int nt = 0; nt < 13; nt++) {
    s16x8 bk0 = *(const s16x8*)&sh[(nt*16 + lq)*72 + quad*8];
    s16x8 bk1 = *(const s16x8*)&sh[(nt*16 + lq)*72 + 32 + quad*8];
    f32x4 c = {};
    c = mfma16(aq0, bk0, c);
    c = mfma16(aq1, bk1, c);
    acc[nt] = c;
  }

  float sm[4] = {0.f, 0.f, 0.f, 0.f};
  #pragma unroll
  for (int nt = 0; nt < 13; nt++) {
    bool valid = (nt < 12) || (lq < 4);
    #pragma unroll
    for (int r = 0; r < 4; r++) {
      float e = valid ? __expf(acc[nt][r]) : 0.f;
      acc[nt][r] = e; sm[r] += e;
    }
  }
  #pragma unroll
  for (int r = 0; r < 4; r++) {
    float s = sm[r];
    s += __shfl_xor(s, 1); s += __shfl_xor(s, 2);
    s += __shfl_xor(s, 4); s += __shfl_xor(s, 8);
    sm[r] = 1.0f / s;
  }

  __syncthreads();

  ushort* Pw = sh + w*(16*232);
  {
    ushort4 zz; zz.x = 0; zz.y = 0; zz.z = 0; zz.w = 0;
    *(ushort4*)&Pw[lq*232 + 208 + quad*4] = zz;
  }
  #pragma unroll
  for (int nt = 0; nt < 13; nt++)
    #pragma unroll
    for (int r = 0; r < 4; r++)
      Pw[(quad*4 + r)*232 + nt*16 + lq] = f2bf(acc[nt][r] * sm[r]);

  const ushort* vb = Vt + ((size_t)((b*FR + f)*NH + h)) * (HD*224);
  f32x4 o[4] = {};
  #pragma unroll
  for (int ks = 0; ks < 7; ks++) {
    s16x8 ap = *(const s16x8*)&Pw[lq*232 + ks*32 + quad*8];
    #pragma unroll
    for (int dt = 0; dt < 4; dt++) {
      s16x8 bv = *(const s16x8*)(vb + (size_t)(dt*16 + lq)*224 + ks*32 + quad*8);
      o[dt] = mfma16(ap, bv, o[dt]);
    }
  }

  #pragma unroll
  for (int dt = 0; dt < 4; dt++)
    #pragma unroll
    for (int r = 0; r < 4; r++)
      Pw[(quad*4 + r)*232 + dt*16 + lq] = f2bf(o[dt][r]);

  {
    int rrow = lane >> 2;
    int cb = (lane & 3) << 4;
    s16x8 xv0 = *(const s16x8*)&Pw[rrow*232 + cb];
    s16x8 xv1 = *(const s16x8*)&Pw[rrow*232 + cb + 8];
    int s = qt*64 + w*16 + rrow;
    if (s < SEQ) {
      ushort* xp = x + (((size_t)b*SEQ + s)*FR + f)*DIM + h*HD + cb;
      *(s16x8*)xp       = xv0;
      *(s16x8*)(xp + 8) = xv1;
    }
  }
}

// ---------------------------------------------------------------------------
// Workspace (ushort units; same known-good map as rounds 8-10):
//  xbf | kvbf (q2 fp32 alias) | qbf (zbf alias) | xqbf (Vt alias) | xkbf
//  WqT | WkvT | WpqT | WprT | WpkvT
// ---------------------------------------------------------------------------
extern "C" void kernel_launch(void* const* d_in, const int* in_sizes, int n_in,
                              void* d_out, int out_size, void* d_ws, size_t ws_size,
                              hipStream_t stream) {
  const float* xq    = (const float*)d_in[0];
  const float* xk    = (const float*)d_in[1];
  const float* Wq    = (const float*)d_in[2];
  const float* Wkv   = (const float*)d_in[3];
  const float* Wpq   = (const float*)d_in[4];
  const float* Wpkv  = (const float*)d_in[5];
  const float* Wproj = (const float*)d_in[6];
  const float* bproj = (const float*)d_in[7];

  float* out   = (float*)d_out;
  float* attn2 = out + (size_t)MTOT*DIM;

  ushort* ws    = (ushort*)d_ws;
  ushort* xbf   = ws;
  ushort* kvbf  = xbf + (size_t)MTOT*FR*DIM;
  float*  q2    = (float*)kvbf;                 // alias, post-stage1
  ushort* qbf   = kvbf + (size_t)MTOT*2*DIM;
  ushort* zbf   = qbf;                          // alias, post-stage1
  ushort* xqbf  = qbf + (size_t)MTOT*DIM;
  ushort* xkbf  = xqbf + (size_t)MTOT*DIM;
  ushort* Vt    = xqbf;                         // alias (dead post-proj)
  ushort* WqT   = xkbf + (size_t)MTOT*DIM;
  ushort* WkvT  = WqT  + (size_t)DIM*DIM;
  ushort* WpqT  = WkvT + (size_t)2*DIM*DIM;
  ushort* WprT  = WpqT + (size_t)DIM*DIM;
  ushort* WpkvT = WprT + (size_t)DIM*DIM;

  dim3 blk(256);
  const int n4 = MTOT*DIM/4;

  cvt_all<<<dim3(4704 + 1440), blk, 0, stream>>>(
      xq, xk, xqbf, xkbf, Wq, Wkv, Wpq, Wproj, Wpkv,
      WqT, WkvT, WpqT, WprT, WpkvT, n4);

  proj_pair<<<dim3(36, (MTOT+127)/128), blk, 0, stream>>>(
      xqbf, xkbf, WqT, WkvT, qbf, kvbf);
  vtrans<<<dim3(BDIM*FR*NH), blk, 0, stream>>>(kvbf, Vt);
  stage1_mfma<<<dim3(BDIM*NH, FR, (SEQ+63)/64), blk, 0, stream>>>(qbf, kvbf, Vt, xbf);
  gemm64<false,true><<<dim3(12, (MTOT+127)/128), blk, 0, stream>>>(
      xbf, WpqT, q2, nullptr, MTOT, DIM, 0.125f);
  // fused stage-2, 64-row tiles (occupancy-fixed)
  stage2_gemm<<<dim3(M2/64, 6), blk, 0, stream>>>(
      xbf, WpkvT, WpkvT + (size_t)DIM*DIM, q2, zbf, attn2);
  gemm64<true,false><<<dim3(12, (MTOT+127)/128), blk, 0, stream>>>(
      zbf, WprT, out, bproj, MTOT, DIM, 1.0f);
}